// Round 5
// baseline (304.204 us; speedup 1.0000x reference)
//
#include <hip/hip_runtime.h>
#include <math.h>

#define B_N 131072
#define NPART 1024
#define PSTRIDE 4160            // 64 colsums + 4096 gram (wave-linear order)
// ---------------- ws layout (float offsets) ----------------
#define WS_PART 0                                  // 1024 * 4160 floats
#define WS_STAT (NPART * PSTRIDE)
#define WS_MT2  (WS_STAT + PSTRIDE)
#define WS_C2   (WS_MT2 + 1280)
#define WS_NH   (WS_C2 + 20)
#define WS_FT   (WS_NH + 400)

__device__ __forceinline__ float gelu_exact(float v) {
    return 0.5f * v * (1.0f + erff(v * 0.70710678118654752440f));
}

// ---------------- pass 1: act + column sums + 64x64 Gram ----------------
// Occupancy-first: __launch_bounds__(256,4) caps VGPR at 128 -> 4 waves/SIMD.
// Grid 1024 -> 4 blocks/CU resident. Each wave owns 32 rows (4 chunks x 8),
// private LDS act tile, no barriers in main loop. Slow-path RBF params live
// in LDS (not registers) so the hot fast path stays under the VGPR cap.
__global__ __launch_bounds__(256, 4) void k_stats(
    const float* __restrict__ x, const float* __restrict__ cen,
    const float* __restrict__ lw, const float* __restrict__ rw,
    const float* __restrict__ linw, float* __restrict__ part)
{
    __shared__ float sAct[4][8][68];   // per-wave act tile, pitch 68
    __shared__ float sGp[64 * 65];     // gram accum, region=lane (pitch 65)
    __shared__ float sCol[4][64];
    __shared__ float sPar[192];        // slow-path params: cen | lw | rw
    const int t = threadIdx.x;
    const int w = t >> 6, lane = t & 63;
    const int rl = lane >> 3;          // row-in-chunk / gram tile row
    const int g  = lane & 7;           // group / gram tile col

    for (int i = t; i < 64 * 65; i += 256) sGp[i] = 0.0f;
    if (t < 64) { sPar[t] = cen[t]; sPar[64 + t] = lw[t]; sPar[128 + t] = rw[t]; }

    const float lin = linw[g];
    // fused uniformity check + fast-table build (scalar temps only)
    const float c0 = cen[g * 8];
    const float delta = cen[g * 8 + 1] - c0;
    float s0 = expf(lw[g * 8]) + 1e-6f;
    const float nh0 = -0.5f / (s0 * s0);
    const float k1c = -2.0f * delta * nh0;
    bool uni = true;
    float W_[8];
#pragma unroll
    for (int k = 0; k < 8; ++k) {
        float ck = cen[g * 8 + k];
        float cke = c0 + (float)k * delta;
        uni = uni && (fabsf(ck - cke) <= 1e-5f * (1.0f + fabsf(cke)));
        float sk = expf(lw[g * 8 + k]) + 1e-6f;
        float nhk = -0.5f / (sk * sk);
        uni = uni && (fabsf(nhk - nh0) <= 1e-6f * fabsf(nh0));
        float kd = (float)k * delta;
        W_[k] = rw[g * 8 + k] * __expf(nh0 * kd * kd);
    }
    const bool fast = (bool)__all((int)uni);

    float sumA[8];
#pragma unroll
    for (int f = 0; f < 8; ++f) sumA[f] = 0.0f;
    float Ga[8][8];
#pragma unroll
    for (int a = 0; a < 8; ++a)
#pragma unroll
        for (int b = 0; b < 8; ++b) Ga[a][b] = 0.0f;

    __syncthreads();   // sGp zeroed + sPar staged before use

    const size_t wrow0 = ((size_t)(blockIdx.x * 4 + w)) * 32;
    float (*buf)[68] = sAct[w];

    // prefetch chunk 0 (coalesced: lane=rl*8+g -> 2KB contiguous per wave)
    const float* xr0 = x + (wrow0 + rl) * 64 + g * 8;
    float4 pv0 = *(const float4*)xr0;
    float4 pv1 = *(const float4*)(xr0 + 4);

    if (fast) {
#pragma unroll 1
        for (int c = 0; c < 4; ++c) {
            float xv[8] = {pv0.x, pv0.y, pv0.z, pv0.w, pv1.x, pv1.y, pv1.z, pv1.w};
            if (c < 3) {
                const float* xn = x + (wrow0 + (c + 1) * 8 + rl) * 64 + g * 8;
                pv0 = *(const float4*)xn;
                pv1 = *(const float4*)(xn + 4);
            }
            float act[8];
#pragma unroll
            for (int f = 0; f < 8; ++f) {
                float v = xv[f];
                float dv = v - c0;
                float E0 = __expf(nh0 * dv * dv);
                float T  = __expf(k1c * dv);
                float poly = W_[7];
#pragma unroll
                for (int k = 6; k >= 0; --k) poly = poly * T + W_[k];
                act[f] = lin * v + E0 * poly;
            }
#pragma unroll
            for (int f = 0; f < 8; ++f) sumA[f] += act[f];
            *(float4*)&buf[rl][g * 8]     = make_float4(act[0], act[1], act[2], act[3]);
            *(float4*)&buf[rl][g * 8 + 4] = make_float4(act[4], act[5], act[6], act[7]);
#pragma unroll
            for (int r = 0; r < 8; ++r) {
                const float4 va  = *(const float4*)&buf[r][rl * 8];
                const float4 va2 = *(const float4*)&buf[r][rl * 8 + 4];
                const float4 vb  = *(const float4*)&buf[r][g * 8];
                const float4 vb2 = *(const float4*)&buf[r][g * 8 + 4];
                const float A0 = va.x,  A1 = va.y,  A2 = va.z,  A3 = va.w;
                const float A4 = va2.x, A5 = va2.y, A6 = va2.z, A7 = va2.w;
                const float B0 = vb.x,  B1 = vb.y,  B2 = vb.z,  B3 = vb.w;
                const float B4 = vb2.x, B5 = vb2.y, B6 = vb2.z, B7 = vb2.w;
                Ga[0][0] += A0*B0; Ga[0][1] += A0*B1; Ga[0][2] += A0*B2; Ga[0][3] += A0*B3;
                Ga[0][4] += A0*B4; Ga[0][5] += A0*B5; Ga[0][6] += A0*B6; Ga[0][7] += A0*B7;
                Ga[1][0] += A1*B0; Ga[1][1] += A1*B1; Ga[1][2] += A1*B2; Ga[1][3] += A1*B3;
                Ga[1][4] += A1*B4; Ga[1][5] += A1*B5; Ga[1][6] += A1*B6; Ga[1][7] += A1*B7;
                Ga[2][0] += A2*B0; Ga[2][1] += A2*B1; Ga[2][2] += A2*B2; Ga[2][3] += A2*B3;
                Ga[2][4] += A2*B4; Ga[2][5] += A2*B5; Ga[2][6] += A2*B6; Ga[2][7] += A2*B7;
                Ga[3][0] += A3*B0; Ga[3][1] += A3*B1; Ga[3][2] += A3*B2; Ga[3][3] += A3*B3;
                Ga[3][4] += A3*B4; Ga[3][5] += A3*B5; Ga[3][6] += A3*B6; Ga[3][7] += A3*B7;
                Ga[4][0] += A4*B0; Ga[4][1] += A4*B1; Ga[4][2] += A4*B2; Ga[4][3] += A4*B3;
                Ga[4][4] += A4*B4; Ga[4][5] += A4*B5; Ga[4][6] += A4*B6; Ga[4][7] += A4*B7;
                Ga[5][0] += A5*B0; Ga[5][1] += A5*B1; Ga[5][2] += A5*B2; Ga[5][3] += A5*B3;
                Ga[5][4] += A5*B4; Ga[5][5] += A5*B5; Ga[5][6] += A5*B6; Ga[5][7] += A5*B7;
                Ga[6][0] += A6*B0; Ga[6][1] += A6*B1; Ga[6][2] += A6*B2; Ga[6][3] += A6*B3;
                Ga[6][4] += A6*B4; Ga[6][5] += A6*B5; Ga[6][6] += A6*B6; Ga[6][7] += A6*B7;
                Ga[7][0] += A7*B0; Ga[7][1] += A7*B1; Ga[7][2] += A7*B2; Ga[7][3] += A7*B3;
                Ga[7][4] += A7*B4; Ga[7][5] += A7*B5; Ga[7][6] += A7*B6; Ga[7][7] += A7*B7;
            }
        }
    } else {
#pragma unroll 1
        for (int c = 0; c < 4; ++c) {
            float xv[8] = {pv0.x, pv0.y, pv0.z, pv0.w, pv1.x, pv1.y, pv1.z, pv1.w};
            if (c < 3) {
                const float* xn = x + (wrow0 + (c + 1) * 8 + rl) * 64 + g * 8;
                pv0 = *(const float4*)xn;
                pv1 = *(const float4*)(xn + 4);
            }
            float act[8];
#pragma unroll
            for (int f = 0; f < 8; ++f) act[f] = lin * xv[f];
#pragma unroll 1
            for (int k = 0; k < 8; ++k) {     // params from LDS: no reg arrays
                float ck = sPar[g * 8 + k];
                float sk = expf(sPar[64 + g * 8 + k]) + 1e-6f;
                float nhk = -0.5f / (sk * sk);
                float wk = sPar[128 + g * 8 + k];
#pragma unroll
                for (int f = 0; f < 8; ++f) {
                    float d = xv[f] - ck;
                    act[f] += wk * __expf(d * d * nhk);
                }
            }
#pragma unroll
            for (int f = 0; f < 8; ++f) sumA[f] += act[f];
            *(float4*)&buf[rl][g * 8]     = make_float4(act[0], act[1], act[2], act[3]);
            *(float4*)&buf[rl][g * 8 + 4] = make_float4(act[4], act[5], act[6], act[7]);
#pragma unroll
            for (int r = 0; r < 8; ++r) {
                const float4 va  = *(const float4*)&buf[r][rl * 8];
                const float4 va2 = *(const float4*)&buf[r][rl * 8 + 4];
                const float4 vb  = *(const float4*)&buf[r][g * 8];
                const float4 vb2 = *(const float4*)&buf[r][g * 8 + 4];
                const float A_[8] = {va.x, va.y, va.z, va.w, va2.x, va2.y, va2.z, va2.w};
                const float B_[8] = {vb.x, vb.y, vb.z, vb.w, vb2.x, vb2.y, vb2.z, vb2.w};
#pragma unroll
                for (int a = 0; a < 8; ++a)
#pragma unroll
                    for (int b = 0; b < 8; ++b) Ga[a][b] += A_[a] * B_[b];
            }
        }
    }

    // column sums: fold into lanes 0..7 (lane==g)
#pragma unroll
    for (int off = 32; off >= 8; off >>= 1)
#pragma unroll
        for (int f = 0; f < 8; ++f) sumA[f] += __shfl_down(sumA[f], off, 64);
    if (lane < 8) {
#pragma unroll
        for (int f = 0; f < 8; ++f) sCol[w][lane * 8 + f] = sumA[f];
    }

    // cross-wave gram combine: per-lane region, pitch 65 -> 2-way bank spread
    {
        float* reg = &sGp[lane * 65];
#pragma unroll
        for (int a = 0; a < 8; ++a)
#pragma unroll
            for (int b = 0; b < 8; ++b)
                atomicAdd(&reg[a * 8 + b], Ga[a][b]);
    }
    __syncthreads();

    // plain coalesced store, wave-linear gram order (k_build remaps)
    float* P = part + (size_t)blockIdx.x * PSTRIDE;
    if (t < 64)
        P[t] = sCol[0][t] + sCol[1][t] + sCol[2][t] + sCol[3][t];
    for (int i = t; i < 4096; i += 256)
        P[64 + i] = sGp[i + (i >> 6)];
}

// ---------------- reduce: sum 1024 block-partials -> stat[4160] ----------------
__global__ __launch_bounds__(256) void k_reduce(
    const float* __restrict__ part, float* __restrict__ stat)
{
    __shared__ float sR[4][64];
    const int t = threadIdx.x;
    const int e = t & 63, q = t >> 6;
    const int i = blockIdx.x * 64 + e;
    const float* p = part + (size_t)q * 256 * PSTRIDE + i;
    float s0 = 0.0f, s1 = 0.0f, s2 = 0.0f, s3 = 0.0f;
#pragma unroll 4
    for (int b = 0; b < 256; b += 4) {
        s0 += p[(size_t)(b    ) * PSTRIDE];
        s1 += p[(size_t)(b + 1) * PSTRIDE];
        s2 += p[(size_t)(b + 2) * PSTRIDE];
        s3 += p[(size_t)(b + 3) * PSTRIDE];
    }
    sR[q][e] = (s0 + s1) + (s2 + s3);
    __syncthreads();
    if (t < 64) stat[blockIdx.x * 64 + t] = sR[0][t] + sR[1][t] + sR[2][t] + sR[3][t];
}

// ---------------- build: BN1 fold -> Mt/C, analytic BN2 fold -> Mt2/C2 ----------------
__global__ __launch_bounds__(256) void k_build(
    const float* __restrict__ stat, const float* __restrict__ Wp,
    const float* __restrict__ pb, const float* __restrict__ g1,
    const float* __restrict__ b1, const float* __restrict__ fpW,
    const float* __restrict__ fpb, const float* __restrict__ g2,
    const float* __restrict__ b2, const float* __restrict__ lsu,
    const float* __restrict__ lsl, const float* __restrict__ cen,
    const float* __restrict__ lw, const float* __restrict__ rw,
    const float* __restrict__ linw,
    float* __restrict__ Mt2, float* __restrict__ C2,
    float* __restrict__ nh, float* __restrict__ ftab)
{
    __shared__ float sG[4096];      // Sum over rows of a*a^T (unscaled)
    __shared__ float sAm[64];       // column means
    __shared__ float sa[128], sbb[128];
    __shared__ float sMt[1280];
    __shared__ float sC[20];
    __shared__ float sQ[20][8];
    __shared__ float sDM[20];
    __shared__ float sSc[20];
    __shared__ int   sUni[8];
    const int t = threadIdx.x;
    const float invB = 1.0f / (float)B_N;

    for (int i = t; i < PSTRIDE; i += 256) {
        float s = stat[i];
        if (i < 64) sAm[i] = s * invB;
        else {
            int k2 = i - 64;
            int ln = k2 >> 6, a = (k2 >> 3) & 7, b = k2 & 7;
            int c1 = ((ln >> 3) << 3) | a;      // lane=(rl,g): tile rows rl*8+a
            int c2 = ((ln & 7) << 3) | b;       // tile cols g*8+b
            sG[c1 * 64 + c2] = s;
        }
    }
    __syncthreads();

    // BN1 fold per channel
    if (t < 128) {
        const int g = t >> 4;
        float wv[8];
#pragma unroll
        for (int f = 0; f < 8; ++f) wv[f] = Wp[t * 8 + f];
        float dot = 0.0f;
#pragma unroll
        for (int f = 0; f < 8; ++f) dot += wv[f] * sAm[g * 8 + f];
        const float pbv = pb[t];
        const float mu = pbv + dot;
        float q = 0.0f;
#pragma unroll
        for (int f = 0; f < 8; ++f) {
            float inner = 0.0f;
#pragma unroll
            for (int f2 = 0; f2 < 8; ++f2)
                inner += wv[f2] * sG[(g * 8 + f) * 64 + (g * 8 + f2)];
            q += wv[f] * inner;
        }
        float e2 = pbv * pbv + 2.0f * pbv * dot + q * invB;
        float var = fmaxf(e2 - mu * mu, 0.0f);
        float a = g1[t] * rsqrtf(var + 1e-5f);
        sa[t] = a;
        sbb[t] = b1[t] - mu * a;
    }
    __syncthreads();

    // Mt (BN1 folded) and C
    for (int i = t; i < 1280; i += 256) {
        int gf = i / 20, j = i % 20;
        int g = gf >> 3, f = gf & 7;
        float m = 0.0f;
        for (int o = 0; o < 16; ++o) {
            int c = g * 16 + o;
            m += fpW[j * 128 + c] * sa[c] * Wp[c * 8 + f];
        }
        sMt[i] = m;
    }
    if (t < 20) {
        float cj = fpb[t];
        for (int c = 0; c < 128; ++c)
            cj += fpW[t * 128 + c] * (sa[c] * pb[c] + sbb[c]);
        sC[t] = cj;
    }
    __syncthreads();

    // quadratic forms m_j^T G m_j (split over 8 partial c-ranges) + mean dot
    if (t < 160) {
        int j = t >> 3, pp = t & 7;
        float qp = 0.0f;
        for (int c = pp * 8; c < pp * 8 + 8; ++c) {
            float inner = 0.0f;
            for (int c2 = 0; c2 < 64; ++c2)
                inner += sG[c * 64 + c2] * sMt[c2 * 20 + j];
            qp += sMt[c * 20 + j] * inner;
        }
        sQ[j][pp] = qp;
    } else if (t < 180) {
        int j = t - 160;
        float dm = 0.0f;
        for (int c = 0; c < 64; ++c) dm += sMt[c * 20 + j] * sAm[c];
        sDM[j] = dm;
    }
    __syncthreads();

    // BN2 fold: z stats computed analytically (exact empirical moments)
    if (t < 20) {
        float q = 0.0f;
#pragma unroll
        for (int pp = 0; pp < 8; ++pp) q += sQ[t][pp];
        q *= invB;
        float Cj  = sC[t];
        float dm  = sDM[t];
        float mu2 = Cj + dm;
        float Ez2 = Cj * Cj + 2.0f * Cj * dm + q;
        float var = fmaxf(Ez2 - mu2 * mu2, 0.0f);
        float sc = g2[t] * rsqrtf(var + 1e-5f);
        sSc[t] = sc;
        C2[t] = Cj * sc + (b2[t] - mu2 * sc);
    }
    __syncthreads();
    for (int i = t; i < 1280; i += 256) Mt2[i] = sMt[i] * sSc[i % 20];

    // fuzzy tables
    for (int i = t; i < 200; i += 256) {
        float su = expf(lsu[i]) + 1e-6f;
        float sl = fminf(expf(lsl[i]) + 1e-6f, 0.9f * su);
        nh[i]       = -0.5f / (su * su);
        nh[200 + i] = -0.5f / (sl * sl);
    }

    // fast-act table for k_out
    if (t < 8) {
        int gg = t;
        float c0 = cen[gg * 8];
        float delta = cen[gg * 8 + 1] - c0;
        float s0 = expf(lw[gg * 8]) + 1e-6f;
        float nh0 = -0.5f / (s0 * s0);
        bool uni = true;
        float Wk[8];
#pragma unroll
        for (int k = 0; k < 8; ++k) {
            float ck = cen[gg * 8 + k];
            float cke = c0 + (float)k * delta;
            uni = uni && (fabsf(ck - cke) <= 1e-5f * (1.0f + fabsf(cke)));
            float sk = expf(lw[gg * 8 + k]) + 1e-6f;
            float nhk = -0.5f / (sk * sk);
            uni = uni && (fabsf(nhk - nh0) <= 1e-6f * fabsf(nh0));
            float kd = (float)k * delta;
            Wk[k] = rw[gg * 8 + k] * __expf(nh0 * kd * kd);
        }
        ftab[gg * 12 + 0] = c0;
        ftab[gg * 12 + 1] = -2.0f * delta * nh0;
        ftab[gg * 12 + 2] = nh0;
        ftab[gg * 12 + 3] = linw[gg];
#pragma unroll
        for (int k = 0; k < 8; ++k) ftab[gg * 12 + 4 + k] = Wk[k];
        sUni[gg] = uni ? 1 : 0;
    }
    __syncthreads();
    if (t == 0) {
        int f = 1;
        for (int gg = 0; gg < 8; ++gg) f &= sUni[gg];
        ftab[96] = (float)f;
    }
}

// ---------------- pass 2: lane-pair split: act -> z~ -> GELU -> fuzzy -> head ----------
// Each ROW is handled by a lane pair (t, t^1): each thread does 4 groups of the
// dot (combine via shfl_xor), 10 of 20 GELUs (exchanged), 5 of 10 rules.
// Doubles resident waves (2048 -> 4096) to hide exp/erf latency.
__global__ __launch_bounds__(256, 4) void k_out(
    const float* __restrict__ x, const float* __restrict__ cen,
    const float* __restrict__ lw, const float* __restrict__ rw,
    const float* __restrict__ linw, const float* __restrict__ Mt2,
    const float* __restrict__ C2, const float* __restrict__ nh,
    const float* __restrict__ fzc, const float* __restrict__ hW,
    const float* __restrict__ hb, const float* __restrict__ ftab,
    float* __restrict__ out)
{
    __shared__ __align__(16) float sMt[1280];
    __shared__ float sC[20];
    __shared__ float sTab[97];
    __shared__ float sNh[400], sFz[200], sHw[10];
    __shared__ __align__(16) float4 sRbf[64];
    __shared__ float sLin[8];
    const int t = threadIdx.x;
    for (int i = t; i < 1280; i += 256) sMt[i] = Mt2[i];
    if (t < 20) sC[t] = C2[t];
    if (t < 97) sTab[t] = ftab[t];
    for (int i = t; i < 400; i += 256) sNh[i] = nh[i];
    if (t < 200) sFz[t] = fzc[t];
    if (t < 10) sHw[t] = hW[t];
    if (t < 64) {
        float s = expf(lw[t]) + 1e-6f;
        sRbf[t] = make_float4(cen[t], rw[t], -0.5f / (s * s), 0.0f);
    }
    if (t < 8) sLin[t] = linw[t];
    __syncthreads();
    const bool fast = (sTab[96] > 0.5f);

    const int h = t & 1;                       // pair half
    const int row = (blockIdx.x * 256 + t) >> 1;
    const float* xr = x + (size_t)row * 64 + h * 32;

    float zp[20];
#pragma unroll
    for (int j = 0; j < 20; ++j) zp[j] = h ? 0.0f : sC[j];

#pragma unroll 1
    for (int gg = 0; gg < 4; ++gg) {
        const int g = h * 4 + gg;
        float4 v0 = *(const float4*)(xr + gg * 8);
        float4 v1 = *(const float4*)(xr + gg * 8 + 4);
        float xv[8] = {v0.x, v0.y, v0.z, v0.w, v1.x, v1.y, v1.z, v1.w};
        float act[8];
        if (fast) {
            const float c0  = sTab[g * 12 + 0];
            const float k1c = sTab[g * 12 + 1];
            const float nh0 = sTab[g * 12 + 2];
            const float lin = sTab[g * 12 + 3];
#pragma unroll
            for (int f = 0; f < 8; ++f) {
                float v = xv[f];
                float dv = v - c0;
                float E0 = __expf(nh0 * dv * dv);
                float T  = __expf(k1c * dv);
                float poly = sTab[g * 12 + 11];
#pragma unroll
                for (int k = 6; k >= 0; --k) poly = poly * T + sTab[g * 12 + 4 + k];
                act[f] = lin * v + E0 * poly;
            }
        } else {
            float lin = sLin[g];
#pragma unroll
            for (int f = 0; f < 8; ++f) act[f] = lin * xv[f];
#pragma unroll 1
            for (int k = 0; k < 8; ++k) {
                float4 pr = sRbf[g * 8 + k];
#pragma unroll
                for (int f = 0; f < 8; ++f) {
                    float d = xv[f] - pr.x;
                    act[f] += pr.y * __expf(d * d * pr.z);
                }
            }
        }
#pragma unroll 1
        for (int f = 0; f < 8; ++f) {
            float av = act[f];
            const float4* m4 = (const float4*)(sMt + (g * 8 + f) * 20);
            float4 ma = m4[0], mb = m4[1], mc = m4[2], md = m4[3], me = m4[4];
            zp[0] += av * ma.x; zp[1] += av * ma.y; zp[2] += av * ma.z; zp[3] += av * ma.w;
            zp[4] += av * mb.x; zp[5] += av * mb.y; zp[6] += av * mb.z; zp[7] += av * mb.w;
            zp[8] += av * mc.x; zp[9] += av * mc.y; zp[10] += av * mc.z; zp[11] += av * mc.w;
            zp[12] += av * md.x; zp[13] += av * md.y; zp[14] += av * md.z; zp[15] += av * md.w;
            zp[16] += av * me.x; zp[17] += av * me.y; zp[18] += av * me.z; zp[19] += av * me.w;
        }
    }

    // combine partial dots across the pair: both lanes get full z~ (BN2 folded)
#pragma unroll
    for (int j = 0; j < 20; ++j) zp[j] += __shfl_xor(zp[j], 1, 64);

    // split GELU 10/10 and exchange (compile-time reg indices only; h via cndmask)
    float zlo[10], zhi[10];
#pragma unroll
    for (int jj = 0; jj < 10; ++jj) {
        float vmine = h ? zp[10 + jj] : zp[jj];
        float gv = gelu_exact(vmine);
        float ov = __shfl_xor(gv, 1, 64);
        zlo[jj] = h ? ov : gv;
        zhi[jj] = h ? gv : ov;
    }

    // fuzzy: this thread handles rules r = h*5 .. h*5+4
    float acc = 0.0f;
#pragma unroll 1
    for (int rr = 0; rr < 5; ++rr) {
        const int r = h * 5 + rr;
        float u = 0.0f, l = 0.0f;
#pragma unroll
        for (int j = 0; j < 20; ++j) {
            float zj = (j < 10) ? zlo[j] : zhi[j - 10];
            float cx = sFz[r * 20 + j];
            float pu = sNh[r * 20 + j];
            float pl = sNh[200 + r * 20 + j];
            float d = zj - cx;
            float dd = d * d;
            u += __expf(dd * pu);
            l += __expf(dd * pl);
        }
        acc += sHw[r] * 0.025f * (u + l);
    }
    acc += __shfl_xor(acc, 1, 64);
    if (h == 0) out[row] = acc + hb[0];
}

// ---------------- launcher ----------------
extern "C" void kernel_launch(void* const* d_in, const int* in_sizes, int n_in,
                              void* d_out, int out_size, void* d_ws, size_t ws_size,
                              hipStream_t stream) {
    const float* x    = (const float*)d_in[0];
    const float* cen  = (const float*)d_in[1];
    const float* lw   = (const float*)d_in[2];
    const float* rw   = (const float*)d_in[3];
    const float* linw = (const float*)d_in[4];
    const float* Wp   = (const float*)d_in[5];
    const float* pb   = (const float*)d_in[6];
    const float* g1   = (const float*)d_in[7];
    const float* b1   = (const float*)d_in[8];
    const float* fpW  = (const float*)d_in[9];
    const float* fpb  = (const float*)d_in[10];
    const float* g2   = (const float*)d_in[11];
    const float* b2   = (const float*)d_in[12];
    const float* fzc  = (const float*)d_in[13];
    const float* lsu  = (const float*)d_in[14];
    const float* lsl  = (const float*)d_in[15];
    const float* hW   = (const float*)d_in[16];
    const float* hb   = (const float*)d_in[17];

    float* ws   = (float*)d_ws;
    float* part = ws + WS_PART;
    float* stat = ws + WS_STAT;
    float* Mt2  = ws + WS_MT2;
    float* C2   = ws + WS_C2;
    float* nh   = ws + WS_NH;
    float* ftab = ws + WS_FT;
    float* outp = (float*)d_out;

    k_stats<<<1024, 256, 0, stream>>>(x, cen, lw, rw, linw, part);
    k_reduce<<<65, 256, 0, stream>>>(part, stat);
    k_build<<<1, 256, 0, stream>>>(stat, Wp, pb, g1, b1, fpW, fpb, g2, b2,
                                   lsu, lsl, cen, lw, rw, linw,
                                   Mt2, C2, nh, ftab);
    k_out<<<1024, 256, 0, stream>>>(x, cen, lw, rw, linw, Mt2, C2, nh, fzc,
                                    hW, hb, ftab, outp);
}

// Round 6
// 197.319 us; speedup vs baseline: 1.5417x; 1.5417x over previous
//
#include <hip/hip_runtime.h>
#include <hip/hip_fp16.h>
#include <math.h>

#define B_N 131072
#define NSTRIPE1 512            // k_moments blocks / stripes
#define NSTRIPE2 512            // k_z blocks / stripes

// ---------------- ws layout (float offsets) ----------------
#define WS_P1   0                                   // part1[512][352]
#define WS_P2   (NSTRIPE1 * 352)                    // 180224: part2[512][40]
#define WS_MT   (WS_P2 + NSTRIPE2 * 40)             // 200704: Mt[64][20]
#define WS_C    (WS_MT + 1280)                      // 201984: C[20]
#define WS_NH   (WS_C + 20)                         // 202004: nhu[200], nhl[200]
#define WS_ACTH (WS_NH + 400)                       // 202404: act fp16 [B][64] (B*32 floats)
#define WS_Z    (WS_ACTH + (size_t)B_N * 32)        // z col-major [20][B]

struct alignas(16) H8 { __half2 a, b, c, d; };

__device__ __forceinline__ float gelu_exact(float v) {
    return 0.5f * v * (1.0f + erff(v * 0.70710678118654752440f));
}

// ---------------- pass 1: RBF -> act (fp16 store) + act moments ----------------
// Per-block PLAIN stripe store (no memset, no atomics). Fast path: uniform
// centre grid + shared width per group -> 2 exps + Horner. Wave-uniform branch.
__global__ __launch_bounds__(256) void k_moments(
    const float* __restrict__ x, const float* __restrict__ cen,
    const float* __restrict__ lw, const float* __restrict__ rw,
    const float* __restrict__ linw, __half* __restrict__ act_h,
    float* __restrict__ part1)
{
    __shared__ float sAcc[4][8][44];
    const int t = threadIdx.x;
    const int g = t & 7;
    const int rl = t >> 3;

    float c_[8], nh_[8], w_[8];
#pragma unroll
    for (int k = 0; k < 8; ++k) {
        c_[k] = cen[g * 8 + k];
        float s = expf(lw[g * 8 + k]) + 1e-6f;
        nh_[k] = -0.5f / (s * s);
        w_[k] = rw[g * 8 + k];
    }
    const float lin = linw[g];
    const float c0 = c_[0], nh0 = nh_[0];
    const float delta = c_[1] - c_[0];

    bool uni = true;
#pragma unroll
    for (int k = 0; k < 8; ++k) {
        float ck = c0 + (float)k * delta;
        uni = uni && (fabsf(c_[k] - ck) <= 1e-5f * (1.0f + fabsf(ck)));
        uni = uni && (fabsf(nh_[k] - nh0) <= 1e-6f * fabsf(nh0));
    }
    const bool fast = (bool)__all((int)uni);

    float W_[8];
    float k1 = 0.0f;
    if (fast) {
        k1 = -2.0f * delta * nh0;
#pragma unroll
        for (int k = 0; k < 8; ++k) {
            float kd = (float)k * delta;
            W_[k] = w_[k] * __expf(nh0 * kd * kd);
        }
    }

    float sumA[8], P[36];
#pragma unroll
    for (int f = 0; f < 8; ++f) sumA[f] = 0.0f;
#pragma unroll
    for (int i = 0; i < 36; ++i) P[i] = 0.0f;

    if (fast) {
#pragma unroll 1
        for (int row = blockIdx.x * 32 + rl; row < B_N; row += gridDim.x * 32) {
            const float* xr = x + (size_t)row * 64 + g * 8;
            float4 v0 = *(const float4*)(xr);
            float4 v1 = *(const float4*)(xr + 4);
            float xv[8] = {v0.x, v0.y, v0.z, v0.w, v1.x, v1.y, v1.z, v1.w};
            float act[8];
#pragma unroll
            for (int f = 0; f < 8; ++f) {
                float v = xv[f];
                float dv = v - c0;
                float E0 = __expf(nh0 * dv * dv);
                float T  = __expf(k1 * dv);
                float poly = W_[7];
#pragma unroll
                for (int k = 6; k >= 0; --k) poly = poly * T + W_[k];
                act[f] = lin * v + E0 * poly;
            }
            H8 h;
            h.a = __floats2half2_rn(act[0], act[1]);
            h.b = __floats2half2_rn(act[2], act[3]);
            h.c = __floats2half2_rn(act[4], act[5]);
            h.d = __floats2half2_rn(act[6], act[7]);
            *(H8*)(act_h + (size_t)row * 64 + g * 8) = h;
            int idx = 0;
#pragma unroll
            for (int f = 0; f < 8; ++f) {
                sumA[f] += act[f];
#pragma unroll
                for (int f2 = 0; f2 <= f; ++f2) { P[idx] += act[f] * act[f2]; ++idx; }
            }
        }
    } else {
#pragma unroll 1
        for (int row = blockIdx.x * 32 + rl; row < B_N; row += gridDim.x * 32) {
            const float* xr = x + (size_t)row * 64 + g * 8;
            float4 v0 = *(const float4*)(xr);
            float4 v1 = *(const float4*)(xr + 4);
            float xv[8] = {v0.x, v0.y, v0.z, v0.w, v1.x, v1.y, v1.z, v1.w};
            float act[8];
#pragma unroll
            for (int f = 0; f < 8; ++f) {
                float v = xv[f];
                float a = lin * v;
#pragma unroll
                for (int k = 0; k < 8; ++k) {
                    float d = v - c_[k];
                    a += w_[k] * __expf(d * d * nh_[k]);
                }
                act[f] = a;
            }
            H8 h;
            h.a = __floats2half2_rn(act[0], act[1]);
            h.b = __floats2half2_rn(act[2], act[3]);
            h.c = __floats2half2_rn(act[4], act[5]);
            h.d = __floats2half2_rn(act[6], act[7]);
            *(H8*)(act_h + (size_t)row * 64 + g * 8) = h;
            int idx = 0;
#pragma unroll
            for (int f = 0; f < 8; ++f) {
                sumA[f] += act[f];
#pragma unroll
                for (int f2 = 0; f2 <= f; ++f2) { P[idx] += act[f] * act[f2]; ++idx; }
            }
        }
    }

#pragma unroll
    for (int off = 32; off >= 8; off >>= 1) {
#pragma unroll
        for (int f = 0; f < 8; ++f) sumA[f] += __shfl_down(sumA[f], off, 64);
#pragma unroll
        for (int i = 0; i < 36; ++i) P[i] += __shfl_down(P[i], off, 64);
    }
    const int wave = t >> 6, lane = t & 63;
    if (lane < 8) {   // lane == g
        float* dst = &sAcc[wave][lane][0];
#pragma unroll
        for (int f = 0; f < 8; ++f) dst[f] = sumA[f];
#pragma unroll
        for (int i = 0; i < 36; ++i) dst[8 + i] = P[i];
    }
    __syncthreads();
    float* S = part1 + (size_t)blockIdx.x * 352;
    for (int i = t; i < 352; i += 256) {
        int gg = i / 44, v = i % 44;
        S[i] = sAcc[0][gg][v] + sAcc[1][gg][v] + sAcc[2][gg][v] + sAcc[3][gg][v];
    }
}

// ---------------- build: reduce stripes -> BN1 fold -> Mt/C, fuzzy tables ----------------
__global__ __launch_bounds__(256) void k_build(
    const float* __restrict__ part1, const float* __restrict__ fpW,
    const float* __restrict__ fpb, const float* __restrict__ g1,
    const float* __restrict__ b1, const float* __restrict__ Wp,
    const float* __restrict__ pb, const float* __restrict__ lsu,
    const float* __restrict__ lsl,
    float* __restrict__ Mt, float* __restrict__ Cc, float* __restrict__ nh)
{
    __shared__ float Am[8][8];
    __shared__ float Sg[8][36];
    __shared__ float a_[128], bb_[128];
    const int t = threadIdx.x;
    for (int i = t; i < 352; i += 256) {
        const float* p = part1 + i;
        float s0 = 0.0f, s1 = 0.0f, s2 = 0.0f, s3 = 0.0f;
#pragma unroll 4
        for (int st = 0; st < NSTRIPE1; st += 4) {
            s0 += p[(st    ) * 352];
            s1 += p[(st + 1) * 352];
            s2 += p[(st + 2) * 352];
            s3 += p[(st + 3) * 352];
        }
        float m = ((s0 + s1) + (s2 + s3)) * (1.0f / B_N);
        int g = i / 44, v = i % 44;
        if (v < 8) Am[g][v] = m; else Sg[g][v - 8] = m;
    }
    __syncthreads();
    if (t < 128) {
        const int g = t >> 4;
        float wv[8];
#pragma unroll
        for (int f = 0; f < 8; ++f) wv[f] = Wp[t * 8 + f];
        float dot = 0.0f;
#pragma unroll
        for (int f = 0; f < 8; ++f) dot += wv[f] * Am[g][f];
        const float pbv = pb[t];
        const float mu = pbv + dot;
        float e2 = pbv * pbv + 2.0f * pbv * dot;
        int idx = 0;
#pragma unroll
        for (int f = 0; f < 8; ++f)
#pragma unroll
            for (int f2 = 0; f2 <= f; ++f2) {
                float c2 = (f2 == f) ? 1.0f : 2.0f;
                e2 += c2 * wv[f] * wv[f2] * Sg[g][idx]; ++idx;
            }
        const float var = fmaxf(e2 - mu * mu, 0.0f);
        const float a = g1[t] * rsqrtf(var + 1e-5f);
        a_[t] = a;
        bb_[t] = b1[t] - mu * a;
    }
    __syncthreads();
    for (int i = t; i < 1280; i += 256) {
        int gf = i / 20, j = i % 20;
        int g = gf >> 3, f = gf & 7;
        float m = 0.0f;
        for (int o = 0; o < 16; ++o) {
            int c = g * 16 + o;
            m += fpW[j * 128 + c] * a_[c] * Wp[c * 8 + f];
        }
        Mt[i] = m;
    }
    if (t < 20) {
        float cj = fpb[t];
        for (int c = 0; c < 128; ++c)
            cj += fpW[t * 128 + c] * (a_[c] * pb[c] + bb_[c]);
        Cc[t] = cj;
    }
    for (int i = t; i < 200; i += 256) {
        float su = expf(lsu[i]) + 1e-6f;
        float sl = fminf(expf(lsl[i]) + 1e-6f, 0.9f * su);
        nh[i] = -0.5f / (su * su);
        nh[200 + i] = -0.5f / (sl * sl);
    }
}

// ---------------- pass 2: z = act_h . Mt + C, z-stat stripe (plain store) ----------------
__global__ __launch_bounds__(256) void k_z(
    const __half* __restrict__ act_h, const float* __restrict__ Mt,
    const float* __restrict__ Cc, float* __restrict__ zout,
    float* __restrict__ part2)
{
    __shared__ float sRed[4][40];
    const int t = threadIdx.x;
    const int row = blockIdx.x * 256 + t;

    float zp[20];
#pragma unroll
    for (int j = 0; j < 20; ++j) zp[j] = Cc[j];   // uniform -> s_load

#pragma unroll 1
    for (int g = 0; g < 8; ++g) {
        const H8 h = *(const H8*)(act_h + (size_t)row * 64 + g * 8);
        float2 f0 = __half22float2(h.a), f1 = __half22float2(h.b);
        float2 f2 = __half22float2(h.c), f3 = __half22float2(h.d);
        float a[8] = {f0.x, f0.y, f1.x, f1.y, f2.x, f2.y, f3.x, f3.y};
#pragma unroll
        for (int f = 0; f < 8; ++f) {
            const float* m = Mt + (g * 8 + f) * 20;   // uniform base
            float av = a[f];
#pragma unroll
            for (int j = 0; j < 20; ++j) zp[j] += av * m[j];   // v_fmac v,s,v
        }
    }

#pragma unroll
    for (int j = 0; j < 20; ++j) zout[(size_t)j * B_N + row] = zp[j];

    float s_[20], q_[20];
#pragma unroll
    for (int j = 0; j < 20; ++j) { s_[j] = zp[j]; q_[j] = zp[j] * zp[j]; }
#pragma unroll
    for (int off = 32; off >= 1; off >>= 1) {
#pragma unroll
        for (int j = 0; j < 20; ++j) {
            s_[j] += __shfl_down(s_[j], off, 64);
            q_[j] += __shfl_down(q_[j], off, 64);
        }
    }
    const int wave = t >> 6, lane = t & 63;
    if (lane == 0) {
#pragma unroll
        for (int j = 0; j < 20; ++j) { sRed[wave][j] = s_[j]; sRed[wave][20 + j] = q_[j]; }
    }
    __syncthreads();
    if (t < 40)
        part2[(size_t)blockIdx.x * 40 + t] =
            sRed[0][t] + sRed[1][t] + sRed[2][t] + sRed[3][t];
}

// ---------------- pass 3: reduce z-stats -> BN2 + GELU + fuzzy + head ----------------
__global__ __launch_bounds__(256) void k_out(
    const float* __restrict__ zin, const float* __restrict__ part2,
    const float* __restrict__ g2, const float* __restrict__ b2,
    const float* __restrict__ nh, const float* __restrict__ fzc,
    const float* __restrict__ hW, const float* __restrict__ hb,
    float* __restrict__ out)
{
    __shared__ float sT6[6][40];
    __shared__ float sT[40], sSc[20], sSh[20];
    const int t = threadIdx.x;
    if (t < 240) {
        const int p = t / 40, e = t - p * 40;
        float s = 0.0f;
        for (int st = p; st < NSTRIPE2; st += 6) s += part2[(size_t)st * 40 + e];
        sT6[p][e] = s;
    }
    __syncthreads();
    if (t < 40)
        sT[t] = sT6[0][t] + sT6[1][t] + sT6[2][t] + sT6[3][t] + sT6[4][t] + sT6[5][t];
    __syncthreads();
    if (t < 20) {
        float mu = sT[t] * (1.0f / B_N);
        float var = fmaxf(sT[20 + t] * (1.0f / B_N) - mu * mu, 0.0f);
        float sc = g2[t] * rsqrtf(var + 1e-5f);
        sSc[t] = sc;
        sSh[t] = b2[t] - mu * sc;
    }
    __syncthreads();

    const int row = blockIdx.x * 256 + t;
    float z[20];
#pragma unroll
    for (int j = 0; j < 20; ++j) {
        float v = zin[(size_t)j * B_N + row];
        z[j] = gelu_exact(sSc[j] * v + sSh[j]);
    }
    float acc = hb[0];
#pragma unroll 1
    for (int r = 0; r < 10; ++r) {
        float u = 0.0f, l = 0.0f;
#pragma unroll
        for (int j = 0; j < 20; ++j) {
            float cx = fzc[r * 20 + j];
            float pu = nh[r * 20 + j];
            float pl = nh[200 + r * 20 + j];
            float d = z[j] - cx;
            float dd = d * d;
            u += __expf(dd * pu);
            l += __expf(dd * pl);
        }
        acc += hW[r] * 0.025f * (u + l);
    }
    out[row] = acc;
}

// ---------------- launcher: 4 dispatches, no memset, no atomics ----------------
extern "C" void kernel_launch(void* const* d_in, const int* in_sizes, int n_in,
                              void* d_out, int out_size, void* d_ws, size_t ws_size,
                              hipStream_t stream) {
    const float* x    = (const float*)d_in[0];
    const float* cen  = (const float*)d_in[1];
    const float* lw   = (const float*)d_in[2];
    const float* rw   = (const float*)d_in[3];
    const float* linw = (const float*)d_in[4];
    const float* Wp   = (const float*)d_in[5];
    const float* pb   = (const float*)d_in[6];
    const float* g1   = (const float*)d_in[7];
    const float* b1   = (const float*)d_in[8];
    const float* fpW  = (const float*)d_in[9];
    const float* fpb  = (const float*)d_in[10];
    const float* g2   = (const float*)d_in[11];
    const float* b2   = (const float*)d_in[12];
    const float* fzc  = (const float*)d_in[13];
    const float* lsu  = (const float*)d_in[14];
    const float* lsl  = (const float*)d_in[15];
    const float* hW   = (const float*)d_in[16];
    const float* hb   = (const float*)d_in[17];

    float* ws    = (float*)d_ws;
    float* part1 = ws + WS_P1;
    float* part2 = ws + WS_P2;
    float* Mt    = ws + WS_MT;
    float* Cc    = ws + WS_C;
    float* nh    = ws + WS_NH;
    __half* acth = (__half*)(ws + WS_ACTH);
    float* zbuf  = ws + WS_Z;
    float* outp  = (float*)d_out;

    k_moments<<<NSTRIPE1, 256, 0, stream>>>(x, cen, lw, rw, linw, acth, part1);
    k_build<<<1, 256, 0, stream>>>(part1, fpW, fpb, g1, b1, Wp, pb, lsu, lsl,
                                   Mt, Cc, nh);
    k_z<<<NSTRIPE2, 256, 0, stream>>>(acth, Mt, Cc, zbuf, part2);
    k_out<<<512, 256, 0, stream>>>(zbuf, part2, g2, b2, nh, fzc, hW, hb, outp);
}

// Round 9
// 166.823 us; speedup vs baseline: 1.8235x; 1.1828x over previous
//
#include <hip/hip_runtime.h>
#include <hip/hip_fp16.h>
#include <math.h>

#define B_N 131072

// ---------------- ws layout (float offsets) ----------------
#define WS_P1T  0                                   // part1t[352][1024] transposed
#define WS_ST1  (352 * 1024)                        // 360448: stat1[352] (raw sums)
#define WS_ST2  (WS_ST1 + 352)                      // stat2[64*40]
#define WS_MT   (WS_ST2 + 2560)                     // Mt[64][20]
#define WS_C    (WS_MT + 1280)                      // C[20]
#define WS_NH   (WS_C + 20)                         // nhu[200], nhl[200]
#define WS_ACTH (WS_NH + 400)                       // act fp16 [B][64] (B*32 floats)
#define WS_Z    (WS_ACTH + (size_t)B_N * 32)        // z col-major [20][B]

struct alignas(16) H8 { __half2 a, b, c, d; };

__device__ __forceinline__ float gelu_exact(float v) {
    return 0.5f * v * (1.0f + erff(v * 0.70710678118654752440f));
}

// ---------------- pass 1: RBF -> act (fp16 store) + act moments ----------------
// Grid 1024 (16 waves/CU). Per-block partial stored PLAIN into transposed
// part1t[352][1024] (column = blockIdx): no memset, no global atomics.
__global__ __launch_bounds__(256) void k_moments(
    const float* __restrict__ x, const float* __restrict__ cen,
    const float* __restrict__ lw, const float* __restrict__ rw,
    const float* __restrict__ linw, __half* __restrict__ act_h,
    float* __restrict__ part1t)
{
    __shared__ float sAcc[4][8][44];
    const int t = threadIdx.x;
    const int g = t & 7;
    const int rl = t >> 3;

    float c_[8], nh_[8], w_[8];
#pragma unroll
    for (int k = 0; k < 8; ++k) {
        c_[k] = cen[g * 8 + k];
        float s = expf(lw[g * 8 + k]) + 1e-6f;
        nh_[k] = -0.5f / (s * s);
        w_[k] = rw[g * 8 + k];
    }
    const float lin = linw[g];
    const float c0 = c_[0], nh0 = nh_[0];
    const float delta = c_[1] - c_[0];

    bool uni = true;
#pragma unroll
    for (int k = 0; k < 8; ++k) {
        float ck = c0 + (float)k * delta;
        uni = uni && (fabsf(c_[k] - ck) <= 1e-5f * (1.0f + fabsf(ck)));
        uni = uni && (fabsf(nh_[k] - nh0) <= 1e-6f * fabsf(nh0));
    }
    const bool fast = (bool)__all((int)uni);

    float W_[8];
    float k1 = 0.0f;
    if (fast) {
        k1 = -2.0f * delta * nh0;
#pragma unroll
        for (int k = 0; k < 8; ++k) {
            float kd = (float)k * delta;
            W_[k] = w_[k] * __expf(nh0 * kd * kd);
        }
    }

    float sumA[8], P[36];
#pragma unroll
    for (int f = 0; f < 8; ++f) sumA[f] = 0.0f;
#pragma unroll
    for (int i = 0; i < 36; ++i) P[i] = 0.0f;

    if (fast) {
#pragma unroll 1
        for (int row = blockIdx.x * 32 + rl; row < B_N; row += gridDim.x * 32) {
            const float* xr = x + (size_t)row * 64 + g * 8;
            float4 v0 = *(const float4*)(xr);
            float4 v1 = *(const float4*)(xr + 4);
            float xv[8] = {v0.x, v0.y, v0.z, v0.w, v1.x, v1.y, v1.z, v1.w};
            float act[8];
#pragma unroll
            for (int f = 0; f < 8; ++f) {
                float v = xv[f];
                float dv = v - c0;
                float E0 = __expf(nh0 * dv * dv);
                float T  = __expf(k1 * dv);
                float poly = W_[7];
#pragma unroll
                for (int k = 6; k >= 0; --k) poly = poly * T + W_[k];
                act[f] = lin * v + E0 * poly;
            }
            H8 h;
            h.a = __floats2half2_rn(act[0], act[1]);
            h.b = __floats2half2_rn(act[2], act[3]);
            h.c = __floats2half2_rn(act[4], act[5]);
            h.d = __floats2half2_rn(act[6], act[7]);
            *(H8*)(act_h + (size_t)row * 64 + g * 8) = h;
            int idx = 0;
#pragma unroll
            for (int f = 0; f < 8; ++f) {
                sumA[f] += act[f];
#pragma unroll
                for (int f2 = 0; f2 <= f; ++f2) { P[idx] += act[f] * act[f2]; ++idx; }
            }
        }
    } else {
#pragma unroll 1
        for (int row = blockIdx.x * 32 + rl; row < B_N; row += gridDim.x * 32) {
            const float* xr = x + (size_t)row * 64 + g * 8;
            float4 v0 = *(const float4*)(xr);
            float4 v1 = *(const float4*)(xr + 4);
            float xv[8] = {v0.x, v0.y, v0.z, v0.w, v1.x, v1.y, v1.z, v1.w};
            float act[8];
#pragma unroll
            for (int f = 0; f < 8; ++f) {
                float v = xv[f];
                float a = lin * v;
#pragma unroll
                for (int k = 0; k < 8; ++k) {
                    float d = v - c_[k];
                    a += w_[k] * __expf(d * d * nh_[k]);
                }
                act[f] = a;
            }
            H8 h;
            h.a = __floats2half2_rn(act[0], act[1]);
            h.b = __floats2half2_rn(act[2], act[3]);
            h.c = __floats2half2_rn(act[4], act[5]);
            h.d = __floats2half2_rn(act[6], act[7]);
            *(H8*)(act_h + (size_t)row * 64 + g * 8) = h;
            int idx = 0;
#pragma unroll
            for (int f = 0; f < 8; ++f) {
                sumA[f] += act[f];
#pragma unroll
                for (int f2 = 0; f2 <= f; ++f2) { P[idx] += act[f] * act[f2]; ++idx; }
            }
        }
    }

#pragma unroll
    for (int off = 32; off >= 8; off >>= 1) {
#pragma unroll
        for (int f = 0; f < 8; ++f) sumA[f] += __shfl_down(sumA[f], off, 64);
#pragma unroll
        for (int i = 0; i < 36; ++i) P[i] += __shfl_down(P[i], off, 64);
    }
    const int wave = t >> 6, lane = t & 63;
    if (lane < 8) {   // lane == g
        float* dst = &sAcc[wave][lane][0];
#pragma unroll
        for (int f = 0; f < 8; ++f) dst[f] = sumA[f];
#pragma unroll
        for (int i = 0; i < 36; ++i) dst[8 + i] = P[i];
    }
    __syncthreads();
    for (int i = t; i < 352; i += 256) {
        const int gg = i / 44, v = i % 44;
        part1t[(size_t)i * 1024 + blockIdx.x] =
            sAcc[0][gg][v] + sAcc[1][gg][v] + sAcc[2][gg][v] + sAcc[3][gg][v];
    }
}

// ---------------- reduce: one wave per element, coalesced 1024-float row sum ----
__global__ __launch_bounds__(256) void k_red(
    const float* __restrict__ part1t, float* __restrict__ stat1)
{
    const int t = threadIdx.x, w = t >> 6, l = t & 63;
    const int gw = blockIdx.x * 4 + w;          // 16 blocks * 4 waves = 64 waves
#pragma unroll 1
    for (int e = gw; e < 352; e += 64) {
        const float* p = part1t + (size_t)e * 1024 + l * 16;
        float4 a = *(const float4*)(p);
        float4 b = *(const float4*)(p + 4);
        float4 c = *(const float4*)(p + 8);
        float4 d = *(const float4*)(p + 12);
        float s = ((a.x + a.y) + (a.z + a.w)) + ((b.x + b.y) + (b.z + b.w))
                + ((c.x + c.y) + (c.z + c.w)) + ((d.x + d.y) + (d.z + d.w));
#pragma unroll
        for (int off = 32; off >= 1; off >>= 1) s += __shfl_down(s, off, 64);
        if (l == 0) stat1[e] = s;
    }
}

// ---------------- build: BN1 fold -> Mt/C, fuzzy tables, zero stat2 ----------------
__global__ __launch_bounds__(256) void k_build(
    const float* __restrict__ stat1, const float* __restrict__ fpW,
    const float* __restrict__ fpb, const float* __restrict__ g1,
    const float* __restrict__ b1, const float* __restrict__ Wp,
    const float* __restrict__ pb, const float* __restrict__ lsu,
    const float* __restrict__ lsl,
    float* __restrict__ Mt, float* __restrict__ Cc, float* __restrict__ nh,
    float* __restrict__ stat2)
{
    __shared__ float Am[8][8];
    __shared__ float Sg[8][36];
    __shared__ float a_[128], bb_[128];
    const int t = threadIdx.x;
    for (int i = t; i < 352; i += 256) {
        float m = stat1[i] * (1.0f / B_N);
        int g = i / 44, v = i % 44;
        if (v < 8) Am[g][v] = m; else Sg[g][v - 8] = m;
    }
    __syncthreads();
    if (t < 128) {
        const int g = t >> 4;
        float wv[8];
#pragma unroll
        for (int f = 0; f < 8; ++f) wv[f] = Wp[t * 8 + f];
        float dot = 0.0f;
#pragma unroll
        for (int f = 0; f < 8; ++f) dot += wv[f] * Am[g][f];
        const float pbv = pb[t];
        const float mu = pbv + dot;
        float e2 = pbv * pbv + 2.0f * pbv * dot;
        int idx = 0;
#pragma unroll
        for (int f = 0; f < 8; ++f)
#pragma unroll
            for (int f2 = 0; f2 <= f; ++f2) {
                float c2 = (f2 == f) ? 1.0f : 2.0f;
                e2 += c2 * wv[f] * wv[f2] * Sg[g][idx]; ++idx;
            }
        const float var = fmaxf(e2 - mu * mu, 0.0f);
        const float a = g1[t] * rsqrtf(var + 1e-5f);
        a_[t] = a;
        bb_[t] = b1[t] - mu * a;
    }
    __syncthreads();
    for (int i = t; i < 1280; i += 256) {
        int gf = i / 20, j = i % 20;
        int g = gf >> 3, f = gf & 7;
        float m = 0.0f;
        for (int o = 0; o < 16; ++o) {
            int c = g * 16 + o;
            m += fpW[j * 128 + c] * a_[c] * Wp[c * 8 + f];
        }
        Mt[i] = m;
    }
    if (t < 20) {
        float cj = fpb[t];
        for (int c = 0; c < 128; ++c)
            cj += fpW[t * 128 + c] * (a_[c] * pb[c] + bb_[c]);
        Cc[t] = cj;
    }
    for (int i = t; i < 200; i += 256) {
        float su = expf(lsu[i]) + 1e-6f;
        float sl = fminf(expf(lsl[i]) + 1e-6f, 0.9f * su);
        nh[i] = -0.5f / (su * su);
        nh[200 + i] = -0.5f / (sl * sl);
    }
    for (int i = t; i < 2560; i += 256) stat2[i] = 0.0f;
}

// ---------------- pass 2: z = act_h . Mt + C, scalar-Mt, 1 row/thread ----------------
__global__ __launch_bounds__(256) void k_z(
    const __half* __restrict__ act_h, const float* __restrict__ Mt,
    const float* __restrict__ Cc, float* __restrict__ zout,
    float* __restrict__ stat2)
{
    __shared__ float sRed[4][40];
    const int t = threadIdx.x;
    const int row = blockIdx.x * 256 + t;

    float zp[20];
#pragma unroll
    for (int j = 0; j < 20; ++j) zp[j] = Cc[j];   // uniform -> s_load

#pragma unroll 1
    for (int g = 0; g < 8; ++g) {
        const H8 h = *(const H8*)(act_h + (size_t)row * 64 + g * 8);
        float2 f0 = __half22float2(h.a), f1 = __half22float2(h.b);
        float2 f2 = __half22float2(h.c), f3 = __half22float2(h.d);
        float a[8] = {f0.x, f0.y, f1.x, f1.y, f2.x, f2.y, f3.x, f3.y};
#pragma unroll
        for (int f = 0; f < 8; ++f) {
            const float* m = Mt + (g * 8 + f) * 20;   // uniform base
            float av = a[f];
#pragma unroll
            for (int j = 0; j < 20; ++j) zp[j] += av * m[j];   // v_fmac v,s,v
        }
    }

#pragma unroll
    for (int j = 0; j < 20; ++j) zout[(size_t)j * B_N + row] = zp[j];

    float s_[20], q_[20];
#pragma unroll
    for (int j = 0; j < 20; ++j) { s_[j] = zp[j]; q_[j] = zp[j] * zp[j]; }
#pragma unroll
    for (int off = 32; off >= 1; off >>= 1) {
#pragma unroll
        for (int j = 0; j < 20; ++j) {
            s_[j] += __shfl_down(s_[j], off, 64);
            q_[j] += __shfl_down(q_[j], off, 64);
        }
    }
    const int wave = t >> 6, lane = t & 63;
    if (lane == 0) {
#pragma unroll
        for (int j = 0; j < 20; ++j) { sRed[wave][j] = s_[j]; sRed[wave][20 + j] = q_[j]; }
    }
    __syncthreads();
    if (t < 40) {
        float v = sRed[0][t] + sRed[1][t] + sRed[2][t] + sRed[3][t];
        atomicAdd(&stat2[(blockIdx.x & 63) * 40 + t], v);
    }
}

// ---------------- pass 3: BN2 + GELU + fuzzy + head ----------------
__global__ __launch_bounds__(256) void k_out(
    const float* __restrict__ zin, const float* __restrict__ stat2,
    const float* __restrict__ g2, const float* __restrict__ b2,
    const float* __restrict__ nh, const float* __restrict__ fzc,
    const float* __restrict__ hW, const float* __restrict__ hb,
    float* __restrict__ out)
{
    __shared__ float sT[40], sSc[20], sSh[20];
    const int t = threadIdx.x;
    if (t < 40) {
        float s = 0.0f;
        for (int st = 0; st < 64; ++st) s += stat2[st * 40 + t];
        sT[t] = s;
    }
    __syncthreads();
    if (t < 20) {
        float mu = sT[t] * (1.0f / B_N);
        float var = fmaxf(sT[20 + t] * (1.0f / B_N) - mu * mu, 0.0f);
        float sc = g2[t] * rsqrtf(var + 1e-5f);
        sSc[t] = sc;
        sSh[t] = b2[t] - mu * sc;
    }
    __syncthreads();

    const int row = blockIdx.x * 256 + t;
    float z[20];
#pragma unroll
    for (int j = 0; j < 20; ++j) {
        float v = zin[(size_t)j * B_N + row];
        z[j] = gelu_exact(sSc[j] * v + sSh[j]);
    }
    float acc = hb[0];
#pragma unroll 1
    for (int r = 0; r < 10; ++r) {
        float u = 0.0f, l = 0.0f;
#pragma unroll
        for (int j = 0; j < 20; ++j) {
            float cx = fzc[r * 20 + j];
            float pu = nh[r * 20 + j];
            float pl = nh[200 + r * 20 + j];
            float d = z[j] - cx;
            float dd = d * d;
            u += __expf(dd * pu);
            l += __expf(dd * pl);
        }
        acc += hW[r] * 0.025f * (u + l);
    }
    out[row] = acc;
}

// ---------------- launcher: 5 dispatches, no memset, no pass-1 atomics ----------------
extern "C" void kernel_launch(void* const* d_in, const int* in_sizes, int n_in,
                              void* d_out, int out_size, void* d_ws, size_t ws_size,
                              hipStream_t stream) {
    const float* x    = (const float*)d_in[0];
    const float* cen  = (const float*)d_in[1];
    const float* lw   = (const float*)d_in[2];
    const float* rw   = (const float*)d_in[3];
    const float* linw = (const float*)d_in[4];
    const float* Wp   = (const float*)d_in[5];
    const float* pb   = (const float*)d_in[6];
    const float* g1   = (const float*)d_in[7];
    const float* b1   = (const float*)d_in[8];
    const float* fpW  = (const float*)d_in[9];
    const float* fpb  = (const float*)d_in[10];
    const float* g2   = (const float*)d_in[11];
    const float* b2   = (const float*)d_in[12];
    const float* fzc  = (const float*)d_in[13];
    const float* lsu  = (const float*)d_in[14];
    const float* lsl  = (const float*)d_in[15];
    const float* hW   = (const float*)d_in[16];
    const float* hb   = (const float*)d_in[17];

    float* ws     = (float*)d_ws;
    float* part1t = ws + WS_P1T;
    float* stat1  = ws + WS_ST1;
    float* stat2  = ws + WS_ST2;
    float* Mt     = ws + WS_MT;
    float* Cc     = ws + WS_C;
    float* nh     = ws + WS_NH;
    __half* acth  = (__half*)(ws + WS_ACTH);
    float* zbuf   = ws + WS_Z;
    float* outp   = (float*)d_out;

    k_moments<<<1024, 256, 0, stream>>>(x, cen, lw, rw, linw, acth, part1t);
    k_red<<<16, 256, 0, stream>>>(part1t, stat1);
    k_build<<<1, 256, 0, stream>>>(stat1, fpW, fpb, g1, b1, Wp, pb, lsu, lsl,
                                   Mt, Cc, nh, stat2);
    k_z<<<512, 256, 0, stream>>>(acth, Mt, Cc, zbuf, stat2);
    k_out<<<512, 256, 0, stream>>>(zbuf, stat2, g2, b2, nh, fzc, hW, hb, outp);
}